// Round 10
// baseline (245.879 us; speedup 1.0000x reference)
//
#include <hip/hip_runtime.h>

#define MODE_QKV 0
#define MODE_S   1
#define MODE_PV  2

typedef __attribute__((ext_vector_type(8))) short short8;
typedef __attribute__((ext_vector_type(4))) float floatx4;

typedef const unsigned __attribute__((address_space(1)))* gp_t;
typedef unsigned __attribute__((address_space(3)))* lp_t;

__device__ __forceinline__ void async16(const void* g, void* l) {
  // stages 16B/lane: LDS dest = wave-uniform base + lane*16
  __builtin_amdgcn_global_load_lds((gp_t)g, (lp_t)l, 16, 0, 0);
}

__device__ __forceinline__ void bar_raw() {
  asm volatile("s_barrier" ::: "memory");
}

__device__ __forceinline__ unsigned short f2bf(float f) {
  union { float f; unsigned u; } x; x.f = f;
  unsigned r = x.u + 0x7fffu + ((x.u >> 16) & 1u);
  return (unsigned short)(r >> 16);
}
__device__ __forceinline__ float bf2f(unsigned short h) {
  union { unsigned u; float f; } x; x.u = ((unsigned)h) << 16;
  return x.f;
}

// ===========================================================================
// Shared swizzled-panel machinery (proven in gemm256 / in-harness since R2:
// SQ_LDS_BANK_CONFLICT 196K vs 6.6M for the old [row][32] layout).
// Panel = [128 rows][64 k] bf16 (16 KB). Physical 16B chunk = logical ^
// (row&7). global_load_lds writes linearly, so the swizzle is applied by
// permuting the per-lane GLOBAL source (XOR involution); frag() applies the
// same XOR on read. 16 frag lanes then hit 8 chunk-slots x 2 = 2 lanes/bank
// (free, m136) instead of 8-way conflicts.
// ===========================================================================

// 8-wave version (gemm256)
__device__ __forceinline__ void stage_half(const unsigned short* gp, long rowbase,
                                           int ldk, int kb, char* region,
                                           int wave, int lane) {
  const int rs = lane >> 3;
  const int kc = ((lane & 7) ^ rs) << 3;
  #pragma unroll
  for (int h = 0; h < 2; h++) {
    const int rr = (h * 8 + wave) * 8 + rs;
    async16(gp + (rowbase + rr) * (long)ldk + kb + kc,
            region + (h * 8 + wave) * 1024);
  }
}

// 4-wave version (gemm_nt / gemm_qkv): same layout, 4 issues/wave
__device__ __forceinline__ void stage_full4(const unsigned short* gp, long rowbase,
                                            int ldk, int kb, char* region,
                                            int wave, int lane) {
  const int rs = lane >> 3;
  const int kc = ((lane & 7) ^ rs) << 3;
  #pragma unroll
  for (int h = 0; h < 4; h++) {
    const int rr = (h * 4 + wave) * 8 + rs;    // 0..127
    async16(gp + (rowbase + rr) * (long)ldk + kb + kc,
            region + (h * 4 + wave) * 1024);
  }
}

__device__ __forceinline__ short8 frag(const char* region, int hr, int ks, int quad) {
  // logical chunk = ks*4+quad (k = ks*32 + quad*8); physical = chunk ^ (hr&7)
  return *(const short8*)(region + hr * 128 + ((((ks << 2) | quad) ^ (hr & 7)) << 4));
}

// ===========================================================================
// gemm_qkv: FUSED q/k/v projection (R9: 58.9 us, -6.3 vs legacy; FETCH -25%).
// R10: swizzled panels -- conflicts were 4.52M/dispatch = 14% of CU time.
// One A-stage + A-frag-read feeds 3 accumulator sets; 512 blocks at
// 2 blocks/CU = exact 1.0 fill. acc[3][4][4] in AGPRs; WRITE_SIZE canary
// stayed exactly 49152 KB in R9 (no spill).
// ===========================================================================
union SmemQKV {
  unsigned short st[4][8192];      // [A,Bq,Bk,Bv] swizzled [128][64] = 64 KB
  unsigned short epi[128 * 136];   // epilogue staging (34816 B)
};

__global__ __launch_bounds__(256, 2)
void gemm_qkv(const unsigned short* __restrict__ A,
              const unsigned short* __restrict__ Wt,   // [3][N][K] k-contig
              const float* __restrict__ b0, const float* __restrict__ b1,
              const float* __restrict__ b2,
              unsigned short* __restrict__ O0, unsigned short* __restrict__ O1,
              unsigned short* __restrict__ O2,
              int M, int N, int K)
{
  __shared__ SmemQKV smem;

  const int tid = threadIdx.x;
  const int wave = tid >> 6, lane = tid & 63;
  const int wm = wave >> 1, wn = wave & 1;
  const int quad = lane >> 4, l16 = lane & 15;

  // ---- XCD-aware 4x4-square swizzle (T = 8*64 = 512, %128==0) ----
  const int gx = gridDim.x, gy = gridDim.y;
  int bm, bn;
  {
    int f = blockIdx.y * gx + blockIdx.x;
    int T = gx * gy;
    int nsq = T >> 7;
    int xcd = f & 7, i = f >> 3;
    int sq = xcd * nsq + (i >> 4);
    int w = i & 15;
    int sqm = sq / (gx >> 2), sqn = sq - sqm * (gx >> 2);
    bm = (sqm * 4 + (w >> 2)) * 128;
    bn = (sqn * 4 + (w & 3)) * 128;
  }

  const unsigned short* Bq = Wt;
  const unsigned short* Bk = Wt + (long)N * K;
  const unsigned short* Bv = Wt + 2L * N * K;

  floatx4 acc[3][4][4];
  #pragma unroll
  for (int s = 0; s < 3; s++)
    #pragma unroll
    for (int i = 0; i < 4; i++)
      #pragma unroll
      for (int j = 0; j < 4; j++)
        acc[s][i][j] = (floatx4){0.f, 0.f, 0.f, 0.f};

  for (int k0 = 0; k0 < K; k0 += 64) {
    stage_full4(A,  bm, K, k0, (char*)smem.st[0], wave, lane);
    stage_full4(Bq, bn, K, k0, (char*)smem.st[1], wave, lane);
    stage_full4(Bk, bn, K, k0, (char*)smem.st[2], wave, lane);
    stage_full4(Bv, bn, K, k0, (char*)smem.st[3], wave, lane);
    __syncthreads();

    #pragma unroll
    for (int ks = 0; ks < 2; ks++) {
      short8 afr[4];
      #pragma unroll
      for (int i = 0; i < 4; i++)
        afr[i] = frag((const char*)smem.st[0], wm * 64 + i * 16 + l16, ks, quad);
      #pragma unroll
      for (int s = 0; s < 3; s++) {
        short8 bfr[4];
        #pragma unroll
        for (int i = 0; i < 4; i++)
          bfr[i] = frag((const char*)smem.st[1 + s], wn * 64 + i * 16 + l16, ks, quad);
        #pragma unroll
        for (int mi = 0; mi < 4; mi++)
          #pragma unroll
          for (int ni = 0; ni < 4; ni++)
            acc[s][mi][ni] = __builtin_amdgcn_mfma_f32_16x16x32_bf16(
                afr[mi], bfr[ni], acc[s][mi][ni], 0, 0, 0);
      }
    }
    __syncthreads();
  }

  // ---- epilogue: 3 sequential passes through the epi buffer ----
  #pragma unroll
  for (int zz = 0; zz < 3; zz++) {
    const float* bias = (zz == 0) ? b0 : ((zz == 1) ? b1 : b2);
    float bi[4];
    #pragma unroll
    for (int ni = 0; ni < 4; ni++) bi[ni] = bias[bn + wn * 64 + ni * 16 + l16];

    #pragma unroll
    for (int ni = 0; ni < 4; ni++) {
      int col = wn * 64 + ni * 16 + l16;
      #pragma unroll
      for (int mi = 0; mi < 4; mi++) {
        int row0 = wm * 64 + mi * 16 + quad * 4;
        if (zz < 2) {
          #pragma unroll
          for (int r = 0; r < 4; r++)
            smem.epi[(row0 + r) * 136 + col] = f2bf(acc[zz][mi][ni][r] + bi[ni]);
        } else {
          #pragma unroll
          for (int r = 0; r < 4; r += 2) {
            unsigned lo = f2bf(acc[2][mi][ni][r] + bi[ni]);
            unsigned hi = f2bf(acc[2][mi][ni][r + 1] + bi[ni]);
            *(unsigned*)&smem.epi[col * 136 + row0 + r] = lo | (hi << 16);
          }
        }
      }
    }
    __syncthreads();

    #pragma unroll
    for (int i = 0; i < 8; i++) {
      int flat = i * 2048 + tid * 8;
      int rr = flat >> 7, cc = flat & 127;
      short8 vline = *(const short8*)&smem.epi[rr * 136 + cc];
      if (zz == 0) {
        *(short8*)&O0[(long)(bm + rr) * N + bn + cc] = vline;
      } else if (zz == 1) {
        *(short8*)&O1[(long)(bm + rr) * N + bn + cc] = vline;
      } else {
        int bb = bm >> 11, s0 = bm & 2047;  // S=2048, tiles don't straddle batch
        *(short8*)&O2[(long)bb * (1024L * 2048) + (long)(bn + rr) * 2048 + s0 + cc] = vline;
      }
    }
    if (zz < 2) __syncthreads();   // epi reused next pass
  }
}

// ===========================================================================
// gemm256: 256x256 8-phase kernel (R4 version). Used ONLY for MODE_S
// (256 blocks = exact 1.0 fill at 1 block/CU; measured -3.5 us vs legacy).
// ===========================================================================

#define MFMA_QUAD(MH, NH)                                                    \
  do {                                                                       \
    _Pragma("unroll")                                                        \
    for (int mi_ = 0; mi_ < 4; mi_++) {                                      \
      _Pragma("unroll")                                                      \
      for (int jj_ = 0; jj_ < 2; jj_++) {                                    \
        _Pragma("unroll")                                                    \
        for (int ks_ = 0; ks_ < 2; ks_++) {                                  \
          acc[MH][mi_][NH][jj_] = __builtin_amdgcn_mfma_f32_16x16x32_bf16(   \
              a[mi_][ks_], b[NH][jj_][ks_], acc[MH][mi_][NH][jj_], 0, 0, 0); \
        }                                                                    \
      }                                                                      \
    }                                                                        \
  } while (0)

template<int MODE>
__global__ __launch_bounds__(512, 1)
void gemm256(const unsigned short* __restrict__ A,
             const unsigned short* __restrict__ Bmat,
             const float* __restrict__ b0, const float* __restrict__ b1,
             const float* __restrict__ b2,
             unsigned short* __restrict__ O0, unsigned short* __restrict__ O1,
             unsigned short* __restrict__ O2, float* __restrict__ Of,
             float* __restrict__ lsum,
             int M, int N, int K, long aZ, long bZ, long cZ, float scale)
{
  __shared__ __attribute__((aligned(128))) char lds[131072];

  const int tid = threadIdx.x;
  const int wave = tid >> 6, lane = tid & 63;
  const int wm = wave >> 2, wn = wave & 3;
  const int quad = lane >> 4, l16 = lane & 15;

  const int gx = gridDim.x, gy = gridDim.y;
  int z, bm, bn;
  {
    int f = (blockIdx.z * gy + blockIdx.y) * gx + blockIdx.x;
    int T = gx * gy * (int)gridDim.z;
    int nsq = T >> 7;
    int xcd = f & 7, i = f >> 3;
    int sq = xcd * nsq + (i >> 4);
    int w = i & 15;
    int spz = (gx >> 2) * (gy >> 2);
    z = sq / spz;
    int sqr = sq - z * spz;
    int sqm = sqr / (gx >> 2), sqn = sqr - sqm * (gx >> 2);
    bm = (sqm * 4 + (w >> 2)) * 256;
    bn = (sqn * 4 + (w & 3)) * 256;
  }

  const unsigned short* Ap = (MODE == MODE_QKV) ? A : (A + (long)z * aZ);
  const unsigned short* Bp = Bmat + (long)z * bZ;

  const int NT = K >> 6;

  stage_half(Ap, bm,       K, 0,  lds +     0, wave, lane);
  stage_half(Bp, bn,       K, 0,  lds + 32768, wave, lane);
  stage_half(Bp, bn + 128, K, 0,  lds + 49152, wave, lane);
  stage_half(Ap, bm + 128, K, 0,  lds + 16384, wave, lane);
  stage_half(Ap, bm,       K, 64, lds + 65536 +     0, wave, lane);
  stage_half(Bp, bn,       K, 64, lds + 65536 + 32768, wave, lane);
  stage_half(Bp, bn + 128, K, 64, lds + 65536 + 49152, wave, lane);
  asm volatile("s_waitcnt vmcnt(6)" ::: "memory");
  bar_raw();

  floatx4 acc[2][4][2][2];
  #pragma unroll
  for (int p = 0; p < 2; p++)
    #pragma unroll
    for (int q2 = 0; q2 < 4; q2++)
      #pragma unroll
      for (int r = 0; r < 2; r++)
        #pragma unroll
        for (int s = 0; s < 2; s++)
          acc[p][q2][r][s] = (floatx4){0.f, 0.f, 0.f, 0.f};

  short8 a[4][2];
  short8 b[2][2][2];

  for (int j = 0; j < NT; j++) {
    char* bufc = lds + ((j & 1) << 16);
    char* bufn = lds + (((j + 1) & 1) << 16);
    const bool lp = (j + 2 >= NT);
    const int kn  = (j + 1) << 6;
    const int kn2 = (j + 2) << 6;

    // ---- phase 0 ----
    #pragma unroll
    for (int mi = 0; mi < 4; mi++)
      #pragma unroll
      for (int ks = 0; ks < 2; ks++)
        a[mi][ks] = frag(bufc, wm * 64 + mi * 16 + l16, ks, quad);
    #pragma unroll
    for (int jj = 0; jj < 2; jj++)
      #pragma unroll
      for (int ks = 0; ks < 2; ks++)
        b[0][jj][ks] = frag(bufc + 32768, wn * 32 + jj * 16 + l16, ks, quad);
    if (j + 1 < NT)
      stage_half(Ap, bm + 128, K, kn, bufn + 16384, wave, lane);
    bar_raw();
    asm volatile("s_waitcnt lgkmcnt(0)" ::: "memory");
    __builtin_amdgcn_s_setprio(1);
    MFMA_QUAD(0, 0);
    __builtin_amdgcn_s_setprio(0);
    bar_raw();

    // ---- phase 1 ----
    #pragma unroll
    for (int jj = 0; jj < 2; jj++)
      #pragma unroll
      for (int ks = 0; ks < 2; ks++)
        b[1][jj][ks] = frag(bufc + 49152, wn * 32 + jj * 16 + l16, ks, quad);
    if (!lp)
      stage_half(Ap, bm, K, kn2, bufc, wave, lane);
    bar_raw();
    asm volatile("s_waitcnt lgkmcnt(0)" ::: "memory");
    __builtin_amdgcn_s_setprio(1);
    MFMA_QUAD(0, 1);
    __builtin_amdgcn_s_setprio(0);
    bar_raw();

    // ---- phase 2 ----
    #pragma unroll
    for (int mi = 0; mi < 4; mi++)
      #pragma unroll
      for (int ks = 0; ks < 2; ks++)
        a[mi][ks] = frag(bufc + 16384, wm * 64 + mi * 16 + l16, ks, quad);
    if (!lp)
      stage_half(Bp, bn, K, kn2, bufc + 32768, wave, lane);
    bar_raw();
    asm volatile("s_waitcnt lgkmcnt(0)" ::: "memory");
    __builtin_amdgcn_s_setprio(1);
    MFMA_QUAD(1, 0);
    __builtin_amdgcn_s_setprio(0);
    bar_raw();

    // ---- phase 3 ----
    if (!lp) {
      stage_half(Bp, bn + 128, K, kn2, bufc + 49152, wave, lane);
      asm volatile("s_waitcnt vmcnt(6)" ::: "memory");
    } else {
      asm volatile("s_waitcnt vmcnt(0)" ::: "memory");
    }
    bar_raw();
    __builtin_amdgcn_s_setprio(1);
    MFMA_QUAD(1, 1);
    __builtin_amdgcn_s_setprio(0);
    bar_raw();
  }

  if (MODE == MODE_PV) {
    #pragma unroll
    for (int mh = 0; mh < 2; mh++)
      #pragma unroll
      for (int mi = 0; mi < 4; mi++) {
        const int row0 = bm + mh * 128 + wm * 64 + mi * 16 + quad * 4;
        float inv[4];
        #pragma unroll
        for (int r = 0; r < 4; r++)
          inv[r] = 1.0f / lsum[(long)z * M + row0 + r];
        #pragma unroll
        for (int nh = 0; nh < 2; nh++)
          #pragma unroll
          for (int jj = 0; jj < 2; jj++) {
            const int col = bn + nh * 128 + wn * 32 + jj * 16 + l16;
            #pragma unroll
            for (int r = 0; r < 4; r++)
              Of[(long)z * cZ + (long)(row0 + r) * N + col] =
                  acc[mh][mi][nh][jj][r] * inv[r];
          }
      }
    return;
  }

  const bool vtrans = (MODE == MODE_QKV) && (z == 2);
  float bi[2][2];
  if (MODE == MODE_QKV) {
    const float* bias = (z == 0) ? b0 : ((z == 1) ? b1 : b2);
    #pragma unroll
    for (int nh = 0; nh < 2; nh++)
      #pragma unroll
      for (int jj = 0; jj < 2; jj++)
        bi[nh][jj] = bias[bn + nh * 128 + wn * 32 + jj * 16 + l16];
  }

  unsigned short* epi = (unsigned short*)lds;
  #pragma unroll
  for (int mh = 0; mh < 2; mh++) {
    #pragma unroll
    for (int mi = 0; mi < 4; mi++) {
      const int r0 = wm * 64 + mi * 16 + quad * 4;
      #pragma unroll
      for (int nh = 0; nh < 2; nh++)
        #pragma unroll
        for (int jj = 0; jj < 2; jj++) {
          const int col = nh * 128 + wn * 32 + jj * 16 + l16;
          if (MODE == MODE_S) {
            #pragma unroll
            for (int r = 0; r < 4; r++)
              epi[(r0 + r) * 264 + col] = f2bf(__expf(acc[mh][mi][nh][jj][r] * scale));
          } else if (!vtrans) {
            #pragma unroll
            for (int r = 0; r < 4; r++)
              epi[(r0 + r) * 264 + col] = f2bf(acc[mh][mi][nh][jj][r] + bi[nh][jj]);
          } else {
            #pragma unroll
            for (int r = 0; r < 4; r += 2) {
              unsigned lo = f2bf(acc[mh][mi][nh][jj][r] + bi[nh][jj]);
              unsigned hi = f2bf(acc[mh][mi][nh][jj][r + 1] + bi[nh][jj]);
              *(unsigned*)&epi[col * 136 + r0 + r] = lo | (hi << 16);
            }
          }
        }
    }
    __syncthreads();

    if (!vtrans) {
      #pragma unroll
      for (int it = 0; it < 8; it++) {
        int flat = it * 4096 + tid * 8;
        int rr = flat >> 8, cc = flat & 255;
        short8 vline = *(const short8*)&epi[rr * 264 + cc];
        long grow = bm + mh * 128 + rr;
        if (MODE == MODE_S) {
          union { short8 v; unsigned short u[8]; } t; t.v = vline;
          float s8 = 0.f;
          #pragma unroll
          for (int jq = 0; jq < 8; jq++) s8 += bf2f(t.u[jq]);
          s8 += __shfl_xor(s8, 1);
          s8 += __shfl_xor(s8, 2);
          s8 += __shfl_xor(s8, 4);
          s8 += __shfl_xor(s8, 8);
          s8 += __shfl_xor(s8, 16);
          if ((lane & 31) == 0) atomicAdd(&lsum[(long)z * M + grow], s8);
          *(short8*)&O0[(long)z * cZ + grow * N + bn + cc] = vline;
        } else {
          unsigned short* O = (z == 0) ? O0 : O1;
          *(short8*)&O[grow * N + bn + cc] = vline;
        }
      }
    } else {
      int bb2 = bm >> 11, s0 = bm & 2047;
      #pragma unroll
      for (int it = 0; it < 8; it++) {
        int flat = it * 4096 + tid * 8;
        int dd = flat >> 7, ss = flat & 127;
        short8 vline = *(const short8*)&epi[dd * 136 + ss];
        *(short8*)&O2[(long)bb2 * (1024L * 2048) + (long)(bn + dd) * 2048 + s0 + mh * 128 + ss] = vline;
      }
    }
    if (mh == 0) __syncthreads();
  }
}

// ===========================================================================
// gemm_nt: 128x128 legacy structure, R10: swizzled [128][64] panels
// (conflicts 6.6M -> expected ~0). Used for PV + fallback path.
// ===========================================================================

union SmemU {
  unsigned short st[2][8192];      // A, B swizzled [128][64] = 32 KB
  unsigned short epi[128 * 136];   // 34816 B
};

template<int MODE>
__global__ __launch_bounds__(256, 4)
void gemm_nt(const unsigned short* __restrict__ A,
             const unsigned short* __restrict__ Bmat,
             const float* __restrict__ b0, const float* __restrict__ b1,
             const float* __restrict__ b2,
             unsigned short* __restrict__ O0, unsigned short* __restrict__ O1,
             unsigned short* __restrict__ O2,
             float* __restrict__ Of, float* __restrict__ lsum,
             int M, int N, int K, long aZ, long bZ, long cZ, float scale)
{
  __shared__ SmemU smem;

  const int tid = threadIdx.x;
  const int wave = tid >> 6, lane = tid & 63;
  const int wm = wave >> 1, wn = wave & 1;
  const int quad = lane >> 4, l16 = lane & 15;

  const int gx = gridDim.x, gy = gridDim.y;
  int z, bm, bn;
  {
    int f = (blockIdx.z * gy + blockIdx.y) * gx + blockIdx.x;
    int T = gx * gy * (int)gridDim.z;
    int nsq = T >> 7;
    int xcd = f & 7, i = f >> 3;
    int sq = xcd * nsq + (i >> 4);
    int w = i & 15;
    int spz = (gx >> 2) * (gy >> 2);
    z = sq / spz;
    int sqr = sq - z * spz;
    int sqm = sqr / (gx >> 2), sqn = sqr - sqm * (gx >> 2);
    bm = (sqm * 4 + (w >> 2)) * 128;
    bn = (sqn * 4 + (w & 3)) * 128;
  }

  const unsigned short* Ap = (MODE == MODE_QKV) ? A : (A + (long)z * aZ);
  const unsigned short* Bp = Bmat + (long)z * bZ;

  floatx4 acc[4][4];
  #pragma unroll
  for (int i = 0; i < 4; i++)
    #pragma unroll
    for (int j = 0; j < 4; j++)
      acc[i][j] = (floatx4){0.f, 0.f, 0.f, 0.f};

  for (int k0 = 0; k0 < K; k0 += 64) {
    stage_full4(Ap, bm, K, k0, (char*)smem.st[0], wave, lane);
    stage_full4(Bp, bn, K, k0, (char*)smem.st[1], wave, lane);
    __syncthreads();

    #pragma unroll
    for (int ks = 0; ks < 2; ks++) {
      short8 afr[4], bfr[4];
      #pragma unroll
      for (int i = 0; i < 4; i++)
        afr[i] = frag((const char*)smem.st[0], wm * 64 + i * 16 + l16, ks, quad);
      #pragma unroll
      for (int i = 0; i < 4; i++)
        bfr[i] = frag((const char*)smem.st[1], wn * 64 + i * 16 + l16, ks, quad);
      #pragma unroll
      for (int mi = 0; mi < 4; mi++)
        #pragma unroll
        for (int ni = 0; ni < 4; ni++)
          acc[mi][ni] = __builtin_amdgcn_mfma_f32_16x16x32_bf16(
              afr[mi], bfr[ni], acc[mi][ni], 0, 0, 0);
    }
    __syncthreads();
  }

  if (MODE == MODE_PV) {
    #pragma unroll
    for (int mi = 0; mi < 4; mi++) {
      int row0 = bm + wm * 64 + mi * 16 + quad * 4;
      float inv[4];
      #pragma unroll
      for (int r = 0; r < 4; r++)
        inv[r] = 1.0f / lsum[(long)z * M + row0 + r];
      #pragma unroll
      for (int ni = 0; ni < 4; ni++) {
        int col = bn + wn * 64 + ni * 16 + l16;
        #pragma unroll
        for (int r = 0; r < 4; r++)
          Of[(long)z * cZ + (long)(row0 + r) * N + col] = acc[mi][ni][r] * inv[r];
      }
    }
    return;
  }

  const bool vtrans = (MODE == MODE_QKV) && (z == 2);
  float bi[4];
  if (MODE == MODE_QKV) {
    const float* bias = (z == 0) ? b0 : ((z == 1) ? b1 : b2);
    #pragma unroll
    for (int ni = 0; ni < 4; ni++) bi[ni] = bias[bn + wn * 64 + ni * 16 + l16];
  }

  #pragma unroll
  for (int ni = 0; ni < 4; ni++) {
    int col = wn * 64 + ni * 16 + l16;
    float bb = (MODE == MODE_QKV) ? bi[ni] : 0.f;
    #pragma unroll
    for (int mi = 0; mi < 4; mi++) {
      int row0 = wm * 64 + mi * 16 + quad * 4;
      if (MODE == MODE_S) {
        #pragma unroll
        for (int r = 0; r < 4; r++)
          smem.epi[(row0 + r) * 136 + col] = f2bf(__expf(acc[mi][ni][r] * scale));
      } else if (!vtrans) {
        #pragma unroll
        for (int r = 0; r < 4; r++)
          smem.epi[(row0 + r) * 136 + col] = f2bf(acc[mi][ni][r] + bb);
      } else {
        #pragma unroll
        for (int r = 0; r < 4; r += 2) {
          unsigned lo = f2bf(acc[mi][ni][r] + bb);
          unsigned hi = f2bf(acc[mi][ni][r + 1] + bb);
          *(unsigned*)&smem.epi[col * 136 + row0 + r] = lo | (hi << 16);
        }
      }
    }
  }
  __syncthreads();

  #pragma unroll
  for (int i = 0; i < 8; i++) {
    int flat = i * 2048 + tid * 8;
    int rr = flat >> 7, cc = flat & 127;
    short8 vline = *(const short8*)&smem.epi[rr * 136 + cc];
    if (MODE == MODE_S) {
      union { short8 v; unsigned short u[8]; } t; t.v = vline;
      float s8 = 0.f;
      #pragma unroll
      for (int j = 0; j < 8; j++) s8 += bf2f(t.u[j]);
      s8 += __shfl_xor(s8, 1);
      s8 += __shfl_xor(s8, 2);
      s8 += __shfl_xor(s8, 4);
      s8 += __shfl_xor(s8, 8);
      if ((lane & 15) == 0) atomicAdd(&lsum[(long)z * M + bm + rr], s8);
      *(short8*)&O0[(long)z * cZ + (long)(bm + rr) * N + bn + cc] = vline;
    } else if (!vtrans) {
      unsigned short* O = (z == 0) ? O0 : O1;
      *(short8*)&O[(long)(bm + rr) * N + bn + cc] = vline;
    } else {
      int bb = bm >> 11, s0 = bm & 2047;
      *(short8*)&O2[(long)bb * (1024L * 2048) + (long)(bn + rr) * 2048 + s0 + cc] = vline;
    }
  }
}

// Fused prep: [0,4096) x fp32->bf16; [4096,7168) W transpose->bf16;
// [7168,7200) zero the 8192-float lsum buffer.
__global__ __launch_bounds__(256)
void prep_kernel(const float* __restrict__ x, unsigned short* __restrict__ xb,
                 const float* __restrict__ W0, const float* __restrict__ W1,
                 const float* __restrict__ W2, unsigned short* __restrict__ Wt,
                 float* __restrict__ lsum) {
  int blk = blockIdx.x;
  if (blk < 4096) {
    long i = ((long)blk * 256 + threadIdx.x) * 8;
    float4 a = *(const float4*)(x + i);
    float4 b = *(const float4*)(x + i + 4);
    union { int4 v; unsigned short u[8]; } t;
    t.u[0] = f2bf(a.x); t.u[1] = f2bf(a.y); t.u[2] = f2bf(a.z); t.u[3] = f2bf(a.w);
    t.u[4] = f2bf(b.x); t.u[5] = f2bf(b.y); t.u[6] = f2bf(b.z); t.u[7] = f2bf(b.w);
    *(int4*)(xb + i) = t.v;
  } else if (blk < 7168) {
    __shared__ float tile[32][33];
    int tt = blk - 4096;
    int zz = tt >> 10, rem = tt & 1023;
    int kb = (rem >> 5) * 32, nb = (rem & 31) * 32;
    const float* W = (zz == 0) ? W0 : ((zz == 1) ? W1 : W2);
    unsigned short* O = Wt + (long)zz * 1024 * 1024;
    int t = threadIdx.x, tr = t >> 5, tc = t & 31;
    #pragma unroll
    for (int i = 0; i < 4; i++)
      tile[tr + i * 8][tc] = W[(long)(kb + tr + i * 8) * 1024 + nb + tc];
    __syncthreads();
    #pragma unroll
    for (int i = 0; i < 4; i++)
      O[(long)(nb + tr + i * 8) * 1024 + kb + tc] = f2bf(tile[tc][tr + i * 8]);
  } else {
    int i = (blk - 7168) * 256 + threadIdx.x;  // 32*256 = 8192 floats
    lsum[i] = 0.f;
  }
}

extern "C" void kernel_launch(void* const* d_in, const int* in_sizes, int n_in,
                              void* d_out, int out_size, void* d_ws, size_t ws_size,
                              hipStream_t stream) {
  const float* x  = (const float*)d_in[0];
  const float* Wq = (const float*)d_in[1];
  const float* bq = (const float*)d_in[2];
  const float* Wk = (const float*)d_in[3];
  const float* bk = (const float*)d_in[4];
  const float* Wv = (const float*)d_in[5];
  const float* bv = (const float*)d_in[6];
  float* out = (float*)d_out;

  const int B = 4, S = 2048, D = 1024;
  const int M = B * S;
  const float scale = 0.03125f;  // 1/sqrt(1024)

  // xb (16 MiB) + Wt (6 MiB) borrow d_out's first 22 MiB; dead before the
  // PV GEMM overwrites all of d_out.
  unsigned short* xb = (unsigned short*)d_out;
  unsigned short* Wt = xb + (size_t)M * D;
  unsigned short* q  = (unsigned short*)d_ws;
  unsigned short* k  = q + (size_t)M * D;
  unsigned short* vT = k + (size_t)M * D;
  unsigned short* P  = vT + (size_t)M * D;

  size_t need_full = ((size_t)3 * M * D + (size_t)B * S * S) * sizeof(unsigned short)
                   + (size_t)M * sizeof(float);
  const bool full = (ws_size >= need_full);
  float* lsum = full ? (float*)(P + (size_t)B * S * S)
                     : (float*)(P + (size_t)S * S);

  prep_kernel<<<7200, 256, 0, stream>>>(x, xb, Wq, Wk, Wv, Wt, lsum);

  // QKV: fused, swizzled panels; 512 blocks at 2 blocks/CU = exact 1.0 fill
  gemm_qkv<<<dim3(D / 128, M / 128), 256, 0, stream>>>(
      xb, Wt, bq, bk, bv, q, k, vT, M, D, D);

  if (full) {
    // S: 256^2 8-phase (256 blocks = exact 1.0 fill)
    gemm256<MODE_S><<<dim3(S / 256, S / 256, B), 512, 0, stream>>>(
        q, k, nullptr, nullptr, nullptr, P, nullptr, nullptr, nullptr, lsum,
        S, S, D, (long)S * D, (long)S * D, (long)S * S, scale);
    // PV: legacy structure, swizzled panels
    gemm_nt<MODE_PV><<<dim3(D / 128, S / 128, B), 256, 0, stream>>>(
        P, vT, nullptr, nullptr, nullptr, nullptr, nullptr, nullptr, out, lsum,
        S, D, S, (long)S * S, (long)D * S, (long)S * D, 1.0f);
  } else {
    for (int b = 0; b < B; b++) {
      const unsigned short* qb = q + (size_t)b * S * D;
      const unsigned short* kb = k + (size_t)b * S * D;
      const unsigned short* vb = vT + (size_t)b * S * D;
      float* ob = out + (size_t)b * S * D;
      gemm_nt<MODE_S><<<dim3(S / 128, S / 128, 1), 256, 0, stream>>>(
          qb, kb, nullptr, nullptr, nullptr, P, nullptr, nullptr, nullptr,
          lsum + (size_t)b * S,
          S, S, D, 0, 0, 0, scale);
      gemm_nt<MODE_PV><<<dim3(D / 128, S / 128, 1), 256, 0, stream>>>(
          P, vb, nullptr, nullptr, nullptr, nullptr, nullptr, nullptr, ob,
          lsum + (size_t)b * S,
          S, D, S, 0, 0, 0, 1.0f);
    }
  }
}

// Round 11
// 225.080 us; speedup vs baseline: 1.0924x; 1.0924x over previous
//
#include <hip/hip_runtime.h>

#define MODE_QKV 0
#define MODE_S   1
#define MODE_PV  2

typedef __attribute__((ext_vector_type(8))) short short8;
typedef __attribute__((ext_vector_type(4))) float floatx4;

typedef const unsigned __attribute__((address_space(1)))* gp_t;
typedef unsigned __attribute__((address_space(3)))* lp_t;

__device__ __forceinline__ void async16(const void* g, void* l) {
  // stages 16B/lane: LDS dest = wave-uniform base + lane*16
  __builtin_amdgcn_global_load_lds((gp_t)g, (lp_t)l, 16, 0, 0);
}

__device__ __forceinline__ void bar_raw() {
  asm volatile("s_barrier" ::: "memory");
}

__device__ __forceinline__ unsigned short f2bf(float f) {
  union { float f; unsigned u; } x; x.f = f;
  unsigned r = x.u + 0x7fffu + ((x.u >> 16) & 1u);
  return (unsigned short)(r >> 16);
}
__device__ __forceinline__ float bf2f(unsigned short h) {
  union { unsigned u; float f; } x; x.u = ((unsigned)h) << 16;
  return x.f;
}

// ===========================================================================
// Swizzled-panel helpers (gemm256 + gemm_nt). Panel = [128][64] bf16, 16 KB;
// physical 16B chunk = logical ^ (row&7), applied on the pre-swizzled GLOBAL
// source (global_load_lds dest is linear) and on the read. NOTE (R10): on
// 2-phase lockstep structures the conflict fix is perf-NEUTRAL (m252 regime-
// gate confirmed in-session: conflicts 14x down, time unchanged) and in the
// fused 3-acc kernel it caused register spills -- so gemm_qkv does NOT use it.
// ===========================================================================

// 8-wave staging (gemm256)
__device__ __forceinline__ void stage_half(const unsigned short* gp, long rowbase,
                                           int ldk, int kb, char* region,
                                           int wave, int lane) {
  const int rs = lane >> 3;
  const int kc = ((lane & 7) ^ rs) << 3;
  #pragma unroll
  for (int h = 0; h < 2; h++) {
    const int rr = (h * 8 + wave) * 8 + rs;
    async16(gp + (rowbase + rr) * (long)ldk + kb + kc,
            region + (h * 8 + wave) * 1024);
  }
}

// 4-wave staging (gemm_nt)
__device__ __forceinline__ void stage_full4(const unsigned short* gp, long rowbase,
                                            int ldk, int kb, char* region,
                                            int wave, int lane) {
  const int rs = lane >> 3;
  const int kc = ((lane & 7) ^ rs) << 3;
  #pragma unroll
  for (int h = 0; h < 4; h++) {
    const int rr = (h * 4 + wave) * 8 + rs;    // 0..127
    async16(gp + (rowbase + rr) * (long)ldk + kb + kc,
            region + (h * 4 + wave) * 1024);
  }
}

__device__ __forceinline__ short8 frag(const char* region, int hr, int ks, int quad) {
  // logical chunk = ks*4+quad (k = ks*32 + quad*8); physical = chunk ^ (hr&7)
  return *(const short8*)(region + hr * 128 + ((((ks << 2) | quad) ^ (hr & 7)) << 4));
}

// ===========================================================================
// gemm_qkv: FUSED q/k/v projection -- R9 VERBATIM (best measured: 58.9 us).
// One A-stage + A-frag-read feeds 3 accumulator sets; 512 blocks at
// 2 blocks/CU = exact 1.0 fill. Linear [op][panel][row*32+chunk] layout:
// the R10 XOR-swizzle variant spilled (+42 MB scratch writes) -- reverted.
// SPILL CANARY: WRITE_SIZE must be exactly 49152 KB.
// ===========================================================================
union SmemQKV {
  unsigned short st[4][2][4096];   // [A,Bq,Bk,Bv][panel p][8 KB] = 64 KB
  unsigned short epi[128 * 136];   // epilogue staging (34816 B)
};

__global__ __launch_bounds__(256, 2)
void gemm_qkv(const unsigned short* __restrict__ A,
              const unsigned short* __restrict__ Wt,   // [3][N][K] k-contig
              const float* __restrict__ b0, const float* __restrict__ b1,
              const float* __restrict__ b2,
              unsigned short* __restrict__ O0, unsigned short* __restrict__ O1,
              unsigned short* __restrict__ O2,
              int M, int N, int K)
{
  __shared__ SmemQKV smem;

  const int tid = threadIdx.x;
  const int wave = tid >> 6, lane = tid & 63;
  const int wm = wave >> 1, wn = wave & 1;
  const int quad = lane >> 4, l16 = lane & 15;

  // ---- XCD-aware 4x4-square swizzle (T = 8*64 = 512, %128==0) ----
  const int gx = gridDim.x, gy = gridDim.y;
  int bm, bn;
  {
    int f = blockIdx.y * gx + blockIdx.x;
    int T = gx * gy;
    int nsq = T >> 7;
    int xcd = f & 7, i = f >> 3;
    int sq = xcd * nsq + (i >> 4);
    int w = i & 15;
    int sqm = sq / (gx >> 2), sqn = sq - sqm * (gx >> 2);
    bm = (sqm * 4 + (w >> 2)) * 128;
    bn = (sqn * 4 + (w & 3)) * 128;
  }

  const unsigned short* Bq = Wt;
  const unsigned short* Bk = Wt + (long)N * K;
  const unsigned short* Bv = Wt + 2L * N * K;

  floatx4 acc[3][4][4];
  #pragma unroll
  for (int s = 0; s < 3; s++)
    #pragma unroll
    for (int i = 0; i < 4; i++)
      #pragma unroll
      for (int j = 0; j < 4; j++)
        acc[s][i][j] = (floatx4){0.f, 0.f, 0.f, 0.f};

  char* asb = (char*)&smem.st[0][0][0] + wave * 1024;
  char* qb  = (char*)&smem.st[1][0][0] + wave * 1024;
  char* kb  = (char*)&smem.st[2][0][0] + wave * 1024;
  char* vb  = (char*)&smem.st[3][0][0] + wave * 1024;

  for (int k0 = 0; k0 < K; k0 += 64) {
    #pragma unroll
    for (int p = 0; p < 2; p++) {
      #pragma unroll
      for (int h = 0; h < 2; h++) {
        int flat = tid + h * 256;          // 16B-chunk index within panel
        int r = flat >> 2, c = (flat & 3) << 3;
        long offA = (long)(bm + r) * K + k0 + p * 32 + c;
        long offB = (long)(bn + r) * K + k0 + p * 32 + c;
        int dst = p * 8192 + h * 4096;
        async16(A  + offA, asb + dst);
        async16(Bq + offB, qb  + dst);
        async16(Bk + offB, kb  + dst);
        async16(Bv + offB, vb  + dst);
      }
    }
    __syncthreads();

    #pragma unroll
    for (int ks = 0; ks < 2; ks++) {
      short8 afr[4];
      #pragma unroll
      for (int i = 0; i < 4; i++)
        afr[i] = *(const short8*)&smem.st[0][ks][(wm * 64 + i * 16 + l16) * 32 + quad * 8];
      #pragma unroll
      for (int s = 0; s < 3; s++) {
        short8 bfr[4];
        #pragma unroll
        for (int i = 0; i < 4; i++)
          bfr[i] = *(const short8*)&smem.st[1 + s][ks][(wn * 64 + i * 16 + l16) * 32 + quad * 8];
        #pragma unroll
        for (int mi = 0; mi < 4; mi++)
          #pragma unroll
          for (int ni = 0; ni < 4; ni++)
            acc[s][mi][ni] = __builtin_amdgcn_mfma_f32_16x16x32_bf16(
                afr[mi], bfr[ni], acc[s][mi][ni], 0, 0, 0);
      }
    }
    __syncthreads();
  }

  // ---- epilogue: 3 sequential passes through the epi buffer ----
  #pragma unroll
  for (int zz = 0; zz < 3; zz++) {
    const float* bias = (zz == 0) ? b0 : ((zz == 1) ? b1 : b2);
    float bi[4];
    #pragma unroll
    for (int ni = 0; ni < 4; ni++) bi[ni] = bias[bn + wn * 64 + ni * 16 + l16];

    #pragma unroll
    for (int ni = 0; ni < 4; ni++) {
      int col = wn * 64 + ni * 16 + l16;
      #pragma unroll
      for (int mi = 0; mi < 4; mi++) {
        int row0 = wm * 64 + mi * 16 + quad * 4;
        if (zz < 2) {
          #pragma unroll
          for (int r = 0; r < 4; r++)
            smem.epi[(row0 + r) * 136 + col] = f2bf(acc[zz][mi][ni][r] + bi[ni]);
        } else {
          #pragma unroll
          for (int r = 0; r < 4; r += 2) {
            unsigned lo = f2bf(acc[2][mi][ni][r] + bi[ni]);
            unsigned hi = f2bf(acc[2][mi][ni][r + 1] + bi[ni]);
            *(unsigned*)&smem.epi[col * 136 + row0 + r] = lo | (hi << 16);
          }
        }
      }
    }
    __syncthreads();

    #pragma unroll
    for (int i = 0; i < 8; i++) {
      int flat = i * 2048 + tid * 8;
      int rr = flat >> 7, cc = flat & 127;
      short8 vline = *(const short8*)&smem.epi[rr * 136 + cc];
      if (zz == 0) {
        *(short8*)&O0[(long)(bm + rr) * N + bn + cc] = vline;
      } else if (zz == 1) {
        *(short8*)&O1[(long)(bm + rr) * N + bn + cc] = vline;
      } else {
        int bb = bm >> 11, s0 = bm & 2047;  // S=2048, tiles don't straddle batch
        *(short8*)&O2[(long)bb * (1024L * 2048) + (long)(bn + rr) * 2048 + s0 + cc] = vline;
      }
    }
    if (zz < 2) __syncthreads();   // epi reused next pass
  }
}

// ===========================================================================
// gemm256: 256x256 8-phase kernel (R4 version). Used ONLY for MODE_S
// (256 blocks = exact 1.0 fill at 1 block/CU; measured -3.5 us vs legacy).
// ===========================================================================

#define MFMA_QUAD(MH, NH)                                                    \
  do {                                                                       \
    _Pragma("unroll")                                                        \
    for (int mi_ = 0; mi_ < 4; mi_++) {                                      \
      _Pragma("unroll")                                                      \
      for (int jj_ = 0; jj_ < 2; jj_++) {                                    \
        _Pragma("unroll")                                                    \
        for (int ks_ = 0; ks_ < 2; ks_++) {                                  \
          acc[MH][mi_][NH][jj_] = __builtin_amdgcn_mfma_f32_16x16x32_bf16(   \
              a[mi_][ks_], b[NH][jj_][ks_], acc[MH][mi_][NH][jj_], 0, 0, 0); \
        }                                                                    \
      }                                                                      \
    }                                                                        \
  } while (0)

template<int MODE>
__global__ __launch_bounds__(512, 1)
void gemm256(const unsigned short* __restrict__ A,
             const unsigned short* __restrict__ Bmat,
             const float* __restrict__ b0, const float* __restrict__ b1,
             const float* __restrict__ b2,
             unsigned short* __restrict__ O0, unsigned short* __restrict__ O1,
             unsigned short* __restrict__ O2, float* __restrict__ Of,
             float* __restrict__ lsum,
             int M, int N, int K, long aZ, long bZ, long cZ, float scale)
{
  __shared__ __attribute__((aligned(128))) char lds[131072];

  const int tid = threadIdx.x;
  const int wave = tid >> 6, lane = tid & 63;
  const int wm = wave >> 2, wn = wave & 3;
  const int quad = lane >> 4, l16 = lane & 15;

  const int gx = gridDim.x, gy = gridDim.y;
  int z, bm, bn;
  {
    int f = (blockIdx.z * gy + blockIdx.y) * gx + blockIdx.x;
    int T = gx * gy * (int)gridDim.z;
    int nsq = T >> 7;
    int xcd = f & 7, i = f >> 3;
    int sq = xcd * nsq + (i >> 4);
    int w = i & 15;
    int spz = (gx >> 2) * (gy >> 2);
    z = sq / spz;
    int sqr = sq - z * spz;
    int sqm = sqr / (gx >> 2), sqn = sqr - sqm * (gx >> 2);
    bm = (sqm * 4 + (w >> 2)) * 256;
    bn = (sqn * 4 + (w & 3)) * 256;
  }

  const unsigned short* Ap = (MODE == MODE_QKV) ? A : (A + (long)z * aZ);
  const unsigned short* Bp = Bmat + (long)z * bZ;

  const int NT = K >> 6;

  stage_half(Ap, bm,       K, 0,  lds +     0, wave, lane);
  stage_half(Bp, bn,       K, 0,  lds + 32768, wave, lane);
  stage_half(Bp, bn + 128, K, 0,  lds + 49152, wave, lane);
  stage_half(Ap, bm + 128, K, 0,  lds + 16384, wave, lane);
  stage_half(Ap, bm,       K, 64, lds + 65536 +     0, wave, lane);
  stage_half(Bp, bn,       K, 64, lds + 65536 + 32768, wave, lane);
  stage_half(Bp, bn + 128, K, 64, lds + 65536 + 49152, wave, lane);
  asm volatile("s_waitcnt vmcnt(6)" ::: "memory");
  bar_raw();

  floatx4 acc[2][4][2][2];
  #pragma unroll
  for (int p = 0; p < 2; p++)
    #pragma unroll
    for (int q2 = 0; q2 < 4; q2++)
      #pragma unroll
      for (int r = 0; r < 2; r++)
        #pragma unroll
        for (int s = 0; s < 2; s++)
          acc[p][q2][r][s] = (floatx4){0.f, 0.f, 0.f, 0.f};

  short8 a[4][2];
  short8 b[2][2][2];

  for (int j = 0; j < NT; j++) {
    char* bufc = lds + ((j & 1) << 16);
    char* bufn = lds + (((j + 1) & 1) << 16);
    const bool lp = (j + 2 >= NT);
    const int kn  = (j + 1) << 6;
    const int kn2 = (j + 2) << 6;

    // ---- phase 0 ----
    #pragma unroll
    for (int mi = 0; mi < 4; mi++)
      #pragma unroll
      for (int ks = 0; ks < 2; ks++)
        a[mi][ks] = frag(bufc, wm * 64 + mi * 16 + l16, ks, quad);
    #pragma unroll
    for (int jj = 0; jj < 2; jj++)
      #pragma unroll
      for (int ks = 0; ks < 2; ks++)
        b[0][jj][ks] = frag(bufc + 32768, wn * 32 + jj * 16 + l16, ks, quad);
    if (j + 1 < NT)
      stage_half(Ap, bm + 128, K, kn, bufn + 16384, wave, lane);
    bar_raw();
    asm volatile("s_waitcnt lgkmcnt(0)" ::: "memory");
    __builtin_amdgcn_s_setprio(1);
    MFMA_QUAD(0, 0);
    __builtin_amdgcn_s_setprio(0);
    bar_raw();

    // ---- phase 1 ----
    #pragma unroll
    for (int jj = 0; jj < 2; jj++)
      #pragma unroll
      for (int ks = 0; ks < 2; ks++)
        b[1][jj][ks] = frag(bufc + 49152, wn * 32 + jj * 16 + l16, ks, quad);
    if (!lp)
      stage_half(Ap, bm, K, kn2, bufc, wave, lane);
    bar_raw();
    asm volatile("s_waitcnt lgkmcnt(0)" ::: "memory");
    __builtin_amdgcn_s_setprio(1);
    MFMA_QUAD(0, 1);
    __builtin_amdgcn_s_setprio(0);
    bar_raw();

    // ---- phase 2 ----
    #pragma unroll
    for (int mi = 0; mi < 4; mi++)
      #pragma unroll
      for (int ks = 0; ks < 2; ks++)
        a[mi][ks] = frag(bufc + 16384, wm * 64 + mi * 16 + l16, ks, quad);
    if (!lp)
      stage_half(Bp, bn, K, kn2, bufc + 32768, wave, lane);
    bar_raw();
    asm volatile("s_waitcnt lgkmcnt(0)" ::: "memory");
    __builtin_amdgcn_s_setprio(1);
    MFMA_QUAD(1, 0);
    __builtin_amdgcn_s_setprio(0);
    bar_raw();

    // ---- phase 3 ----
    if (!lp) {
      stage_half(Bp, bn + 128, K, kn2, bufc + 49152, wave, lane);
      asm volatile("s_waitcnt vmcnt(6)" ::: "memory");
    } else {
      asm volatile("s_waitcnt vmcnt(0)" ::: "memory");
    }
    bar_raw();
    __builtin_amdgcn_s_setprio(1);
    MFMA_QUAD(1, 1);
    __builtin_amdgcn_s_setprio(0);
    bar_raw();
  }

  if (MODE == MODE_PV) {
    #pragma unroll
    for (int mh = 0; mh < 2; mh++)
      #pragma unroll
      for (int mi = 0; mi < 4; mi++) {
        const int row0 = bm + mh * 128 + wm * 64 + mi * 16 + quad * 4;
        float inv[4];
        #pragma unroll
        for (int r = 0; r < 4; r++)
          inv[r] = 1.0f / lsum[(long)z * M + row0 + r];
        #pragma unroll
        for (int nh = 0; nh < 2; nh++)
          #pragma unroll
          for (int jj = 0; jj < 2; jj++) {
            const int col = bn + nh * 128 + wn * 32 + jj * 16 + l16;
            #pragma unroll
            for (int r = 0; r < 4; r++)
              Of[(long)z * cZ + (long)(row0 + r) * N + col] =
                  acc[mh][mi][nh][jj][r] * inv[r];
          }
      }
    return;
  }

  const bool vtrans = (MODE == MODE_QKV) && (z == 2);
  float bi[2][2];
  if (MODE == MODE_QKV) {
    const float* bias = (z == 0) ? b0 : ((z == 1) ? b1 : b2);
    #pragma unroll
    for (int nh = 0; nh < 2; nh++)
      #pragma unroll
      for (int jj = 0; jj < 2; jj++)
        bi[nh][jj] = bias[bn + nh * 128 + wn * 32 + jj * 16 + l16];
  }

  unsigned short* epi = (unsigned short*)lds;
  #pragma unroll
  for (int mh = 0; mh < 2; mh++) {
    #pragma unroll
    for (int mi = 0; mi < 4; mi++) {
      const int r0 = wm * 64 + mi * 16 + quad * 4;
      #pragma unroll
      for (int nh = 0; nh < 2; nh++)
        #pragma unroll
        for (int jj = 0; jj < 2; jj++) {
          const int col = nh * 128 + wn * 32 + jj * 16 + l16;
          if (MODE == MODE_S) {
            #pragma unroll
            for (int r = 0; r < 4; r++)
              epi[(r0 + r) * 264 + col] = f2bf(__expf(acc[mh][mi][nh][jj][r] * scale));
          } else if (!vtrans) {
            #pragma unroll
            for (int r = 0; r < 4; r++)
              epi[(r0 + r) * 264 + col] = f2bf(acc[mh][mi][nh][jj][r] + bi[nh][jj]);
          } else {
            #pragma unroll
            for (int r = 0; r < 4; r += 2) {
              unsigned lo = f2bf(acc[mh][mi][nh][jj][r] + bi[nh][jj]);
              unsigned hi = f2bf(acc[mh][mi][nh][jj][r + 1] + bi[nh][jj]);
              *(unsigned*)&epi[col * 136 + r0 + r] = lo | (hi << 16);
            }
          }
        }
    }
    __syncthreads();

    if (!vtrans) {
      #pragma unroll
      for (int it = 0; it < 8; it++) {
        int flat = it * 4096 + tid * 8;
        int rr = flat >> 8, cc = flat & 255;
        short8 vline = *(const short8*)&epi[rr * 264 + cc];
        long grow = bm + mh * 128 + rr;
        if (MODE == MODE_S) {
          union { short8 v; unsigned short u[8]; } t; t.v = vline;
          float s8 = 0.f;
          #pragma unroll
          for (int jq = 0; jq < 8; jq++) s8 += bf2f(t.u[jq]);
          s8 += __shfl_xor(s8, 1);
          s8 += __shfl_xor(s8, 2);
          s8 += __shfl_xor(s8, 4);
          s8 += __shfl_xor(s8, 8);
          s8 += __shfl_xor(s8, 16);
          if ((lane & 31) == 0) atomicAdd(&lsum[(long)z * M + grow], s8);
          *(short8*)&O0[(long)z * cZ + grow * N + bn + cc] = vline;
        } else {
          unsigned short* O = (z == 0) ? O0 : O1;
          *(short8*)&O[grow * N + bn + cc] = vline;
        }
      }
    } else {
      int bb2 = bm >> 11, s0 = bm & 2047;
      #pragma unroll
      for (int it = 0; it < 8; it++) {
        int flat = it * 4096 + tid * 8;
        int dd = flat >> 7, ss = flat & 127;
        short8 vline = *(const short8*)&epi[dd * 136 + ss];
        *(short8*)&O2[(long)bb2 * (1024L * 2048) + (long)(bn + dd) * 2048 + s0 + mh * 128 + ss] = vline;
      }
    }
    if (mh == 0) __syncthreads();
  }
}

// ===========================================================================
// gemm_nt: 128x128 legacy structure with swizzled [128][64] panels (R10:
// conflicts 6.6M -> <0.5M, time neutral-to--2us on PV). Used for PV +
// fallback path.
// ===========================================================================

union SmemU {
  unsigned short st[2][8192];      // A, B swizzled [128][64] = 32 KB
  unsigned short epi[128 * 136];   // 34816 B
};

template<int MODE>
__global__ __launch_bounds__(256, 4)
void gemm_nt(const unsigned short* __restrict__ A,
             const unsigned short* __restrict__ Bmat,
             const float* __restrict__ b0, const float* __restrict__ b1,
             const float* __restrict__ b2,
             unsigned short* __restrict__ O0, unsigned short* __restrict__ O1,
             unsigned short* __restrict__ O2,
             float* __restrict__ Of, float* __restrict__ lsum,
             int M, int N, int K, long aZ, long bZ, long cZ, float scale)
{
  __shared__ SmemU smem;

  const int tid = threadIdx.x;
  const int wave = tid >> 6, lane = tid & 63;
  const int wm = wave >> 1, wn = wave & 1;
  const int quad = lane >> 4, l16 = lane & 15;

  const int gx = gridDim.x, gy = gridDim.y;
  int z, bm, bn;
  {
    int f = (blockIdx.z * gy + blockIdx.y) * gx + blockIdx.x;
    int T = gx * gy * (int)gridDim.z;
    int nsq = T >> 7;
    int xcd = f & 7, i = f >> 3;
    int sq = xcd * nsq + (i >> 4);
    int w = i & 15;
    int spz = (gx >> 2) * (gy >> 2);
    z = sq / spz;
    int sqr = sq - z * spz;
    int sqm = sqr / (gx >> 2), sqn = sqr - sqm * (gx >> 2);
    bm = (sqm * 4 + (w >> 2)) * 128;
    bn = (sqn * 4 + (w & 3)) * 128;
  }

  const unsigned short* Ap = (MODE == MODE_QKV) ? A : (A + (long)z * aZ);
  const unsigned short* Bp = Bmat + (long)z * bZ;

  floatx4 acc[4][4];
  #pragma unroll
  for (int i = 0; i < 4; i++)
    #pragma unroll
    for (int j = 0; j < 4; j++)
      acc[i][j] = (floatx4){0.f, 0.f, 0.f, 0.f};

  for (int k0 = 0; k0 < K; k0 += 64) {
    stage_full4(Ap, bm, K, k0, (char*)smem.st[0], wave, lane);
    stage_full4(Bp, bn, K, k0, (char*)smem.st[1], wave, lane);
    __syncthreads();

    #pragma unroll
    for (int ks = 0; ks < 2; ks++) {
      short8 afr[4], bfr[4];
      #pragma unroll
      for (int i = 0; i < 4; i++)
        afr[i] = frag((const char*)smem.st[0], wm * 64 + i * 16 + l16, ks, quad);
      #pragma unroll
      for (int i = 0; i < 4; i++)
        bfr[i] = frag((const char*)smem.st[1], wn * 64 + i * 16 + l16, ks, quad);
      #pragma unroll
      for (int mi = 0; mi < 4; mi++)
        #pragma unroll
        for (int ni = 0; ni < 4; ni++)
          acc[mi][ni] = __builtin_amdgcn_mfma_f32_16x16x32_bf16(
              afr[mi], bfr[ni], acc[mi][ni], 0, 0, 0);
    }
    __syncthreads();
  }

  if (MODE == MODE_PV) {
    #pragma unroll
    for (int mi = 0; mi < 4; mi++) {
      int row0 = bm + wm * 64 + mi * 16 + quad * 4;
      float inv[4];
      #pragma unroll
      for (int r = 0; r < 4; r++)
        inv[r] = 1.0f / lsum[(long)z * M + row0 + r];
      #pragma unroll
      for (int ni = 0; ni < 4; ni++) {
        int col = bn + wn * 64 + ni * 16 + l16;
        #pragma unroll
        for (int r = 0; r < 4; r++)
          Of[(long)z * cZ + (long)(row0 + r) * N + col] = acc[mi][ni][r] * inv[r];
      }
    }
    return;
  }

  const bool vtrans = (MODE == MODE_QKV) && (z == 2);
  float bi[4];
  if (MODE == MODE_QKV) {
    const float* bias = (z == 0) ? b0 : ((z == 1) ? b1 : b2);
    #pragma unroll
    for (int ni = 0; ni < 4; ni++) bi[ni] = bias[bn + wn * 64 + ni * 16 + l16];
  }

  #pragma unroll
  for (int ni = 0; ni < 4; ni++) {
    int col = wn * 64 + ni * 16 + l16;
    float bb = (MODE == MODE_QKV) ? bi[ni] : 0.f;
    #pragma unroll
    for (int mi = 0; mi < 4; mi++) {
      int row0 = wm * 64 + mi * 16 + quad * 4;
      if (MODE == MODE_S) {
        #pragma unroll
        for (int r = 0; r < 4; r++)
          smem.epi[(row0 + r) * 136 + col] = f2bf(__expf(acc[mi][ni][r] * scale));
      } else if (!vtrans) {
        #pragma unroll
        for (int r = 0; r < 4; r++)
          smem.epi[(row0 + r) * 136 + col] = f2bf(acc[mi][ni][r] + bb);
      } else {
        #pragma unroll
        for (int r = 0; r < 4; r += 2) {
          unsigned lo = f2bf(acc[mi][ni][r] + bb);
          unsigned hi = f2bf(acc[mi][ni][r + 1] + bb);
          *(unsigned*)&smem.epi[col * 136 + row0 + r] = lo | (hi << 16);
        }
      }
    }
  }
  __syncthreads();

  #pragma unroll
  for (int i = 0; i < 8; i++) {
    int flat = i * 2048 + tid * 8;
    int rr = flat >> 7, cc = flat & 127;
    short8 vline = *(const short8*)&smem.epi[rr * 136 + cc];
    if (MODE == MODE_S) {
      union { short8 v; unsigned short u[8]; } t; t.v = vline;
      float s8 = 0.f;
      #pragma unroll
      for (int j = 0; j < 8; j++) s8 += bf2f(t.u[j]);
      s8 += __shfl_xor(s8, 1);
      s8 += __shfl_xor(s8, 2);
      s8 += __shfl_xor(s8, 4);
      s8 += __shfl_xor(s8, 8);
      if ((lane & 15) == 0) atomicAdd(&lsum[(long)z * M + bm + rr], s8);
      *(short8*)&O0[(long)z * cZ + (long)(bm + rr) * N + bn + cc] = vline;
    } else if (!vtrans) {
      unsigned short* O = (z == 0) ? O0 : O1;
      *(short8*)&O[(long)(bm + rr) * N + bn + cc] = vline;
    } else {
      int bb = bm >> 11, s0 = bm & 2047;
      *(short8*)&O2[(long)bb * (1024L * 2048) + (long)(bn + rr) * 2048 + s0 + cc] = vline;
    }
  }
}

// Fused prep: [0,4096) x fp32->bf16; [4096,7168) W transpose->bf16;
// [7168,7200) zero the 8192-float lsum buffer.
__global__ __launch_bounds__(256)
void prep_kernel(const float* __restrict__ x, unsigned short* __restrict__ xb,
                 const float* __restrict__ W0, const float* __restrict__ W1,
                 const float* __restrict__ W2, unsigned short* __restrict__ Wt,
                 float* __restrict__ lsum) {
  int blk = blockIdx.x;
  if (blk < 4096) {
    long i = ((long)blk * 256 + threadIdx.x) * 8;
    float4 a = *(const float4*)(x + i);
    float4 b = *(const float4*)(x + i + 4);
    union { int4 v; unsigned short u[8]; } t;
    t.u[0] = f2bf(a.x); t.u[1] = f2bf(a.y); t.u[2] = f2bf(a.z); t.u[3] = f2bf(a.w);
    t.u[4] = f2bf(b.x); t.u[5] = f2bf(b.y); t.u[6] = f2bf(b.z); t.u[7] = f2bf(b.w);
    *(int4*)(xb + i) = t.v;
  } else if (blk < 7168) {
    __shared__ float tile[32][33];
    int tt = blk - 4096;
    int zz = tt >> 10, rem = tt & 1023;
    int kb = (rem >> 5) * 32, nb = (rem & 31) * 32;
    const float* W = (zz == 0) ? W0 : ((zz == 1) ? W1 : W2);
    unsigned short* O = Wt + (long)zz * 1024 * 1024;
    int t = threadIdx.x, tr = t >> 5, tc = t & 31;
    #pragma unroll
    for (int i = 0; i < 4; i++)
      tile[tr + i * 8][tc] = W[(long)(kb + tr + i * 8) * 1024 + nb + tc];
    __syncthreads();
    #pragma unroll
    for (int i = 0; i < 4; i++)
      O[(long)(nb + tr + i * 8) * 1024 + kb + tc] = f2bf(tile[tc][tr + i * 8]);
  } else {
    int i = (blk - 7168) * 256 + threadIdx.x;  // 32*256 = 8192 floats
    lsum[i] = 0.f;
  }
}

extern "C" void kernel_launch(void* const* d_in, const int* in_sizes, int n_in,
                              void* d_out, int out_size, void* d_ws, size_t ws_size,
                              hipStream_t stream) {
  const float* x  = (const float*)d_in[0];
  const float* Wq = (const float*)d_in[1];
  const float* bq = (const float*)d_in[2];
  const float* Wk = (const float*)d_in[3];
  const float* bk = (const float*)d_in[4];
  const float* Wv = (const float*)d_in[5];
  const float* bv = (const float*)d_in[6];
  float* out = (float*)d_out;

  const int B = 4, S = 2048, D = 1024;
  const int M = B * S;
  const float scale = 0.03125f;  // 1/sqrt(1024)

  // xb (16 MiB) + Wt (6 MiB) borrow d_out's first 22 MiB; dead before the
  // PV GEMM overwrites all of d_out.
  unsigned short* xb = (unsigned short*)d_out;
  unsigned short* Wt = xb + (size_t)M * D;
  unsigned short* q  = (unsigned short*)d_ws;
  unsigned short* k  = q + (size_t)M * D;
  unsigned short* vT = k + (size_t)M * D;
  unsigned short* P  = vT + (size_t)M * D;

  size_t need_full = ((size_t)3 * M * D + (size_t)B * S * S) * sizeof(unsigned short)
                   + (size_t)M * sizeof(float);
  const bool full = (ws_size >= need_full);
  float* lsum = full ? (float*)(P + (size_t)B * S * S)
                     : (float*)(P + (size_t)S * S);

  prep_kernel<<<7200, 256, 0, stream>>>(x, xb, Wq, Wk, Wv, Wt, lsum);

  // QKV: fused (R9 verbatim); 512 blocks at 2 blocks/CU = exact 1.0 fill
  gemm_qkv<<<dim3(D / 128, M / 128), 256, 0, stream>>>(
      xb, Wt, bq, bk, bv, q, k, vT, M, D, D);

  if (full) {
    // S: 256^2 8-phase (256 blocks = exact 1.0 fill)
    gemm256<MODE_S><<<dim3(S / 256, S / 256, B), 512, 0, stream>>>(
        q, k, nullptr, nullptr, nullptr, P, nullptr, nullptr, nullptr, lsum,
        S, S, D, (long)S * D, (long)S * D, (long)S * S, scale);
    // PV: legacy structure, swizzled panels
    gemm_nt<MODE_PV><<<dim3(D / 128, S / 128, B), 256, 0, stream>>>(
        P, vT, nullptr, nullptr, nullptr, nullptr, nullptr, nullptr, out, lsum,
        S, D, S, (long)S * S, (long)D * S, (long)S * D, 1.0f);
  } else {
    for (int b = 0; b < B; b++) {
      const unsigned short* qb = q + (size_t)b * S * D;
      const unsigned short* kb = k + (size_t)b * S * D;
      const unsigned short* vb = vT + (size_t)b * S * D;
      float* ob = out + (size_t)b * S * D;
      gemm_nt<MODE_S><<<dim3(S / 128, S / 128, 1), 256, 0, stream>>>(
          qb, kb, nullptr, nullptr, nullptr, P, nullptr, nullptr, nullptr,
          lsum + (size_t)b * S,
          S, S, D, 0, 0, 0, scale);
      gemm_nt<MODE_PV><<<dim3(D / 128, S / 128, 1), 256, 0, stream>>>(
          P, vb, nullptr, nullptr, nullptr, nullptr, nullptr, nullptr, ob,
          lsum + (size_t)b * S,
          S, D, S, 0, 0, 0, 1.0f);
    }
  }
}